// Round 4
// baseline (360.964 us; speedup 1.0000x reference)
//
#include <hip/hip_runtime.h>
#include <math.h>

#define G  300
#define NS 256
#define NR 4096
#define CT 32   // interleaved texel channels: 0-7 density, 8-31 app
#define NB 16   // bins per axis
#define NCELL (NB*NB*NB)
#define NSAMP (NR*NS)

typedef _Float16 half16_t;
typedef _Float16 h8 __attribute__((ext_vector_type(8)));
typedef float f4v __attribute__((ext_vector_type(4)));

__device__ __forceinline__ int cell_of(float px, float py, float pz,
                                       float a0x, float a0y, float a0z,
                                       float ivx, float ivy, float ivz)
{
  float gx = (px - a0x) * ivx - 1.f;
  float gy = (py - a0y) * ivy - 1.f;
  float gz = (pz - a0z) * ivz - 1.f;
  int bx = min(max((int)((gx + 1.f) * (0.5f * NB)), 0), NB - 1);
  int by = min(max((int)((gy + 1.f) * (0.5f * NB)), 0), NB - 1);
  int bz = min(max((int)((gz + 1.f) * (0.5f * NB)), 0), NB - 1);
  return (bz * NB + by) * NB + bx;
}

// ---------------------------------------------------------------------------
// Prep planes (fp16 interleave) fused with sample histogram.
// 3*G*G*4 = 1,080,000 threads >= NSAMP = 1,048,576, so thread t also bins sample t.
// ---------------------------------------------------------------------------
__global__ __launch_bounds__(256) void prep_planes_hist(
    const float* __restrict__ dp, const float* __restrict__ ap,
    const float* __restrict__ xyz, const float* __restrict__ aabb,
    half16_t* __restrict__ out, int* __restrict__ hist)
{
  int t = blockIdx.x * blockDim.x + threadIdx.x;
  if (t < 3 * G * G * 4) {
    int m   = t & 3;        // 8-channel part: 0=density, 1..3=app
    int tex = t >> 2;
    int x  = tex % G;
    int yi = tex / G;
    int y  = yi % G;
    int i  = yi / G;
    const size_t GG = (size_t)G * G;
    const float* p = (m == 0) ? (dp + (size_t)(i * 8) * GG + (size_t)y * G + x)
                              : (ap + (size_t)(i * 24 + (m - 1) * 8) * GG + (size_t)y * G + x);
    h8 v;
#pragma unroll
    for (int c = 0; c < 8; ++c) v[c] = (half16_t)p[c * GG];
    *(h8*)(out + (size_t)tex * CT + m * 8) = v;
  }
  if (t < NSAMP) {
    float px = xyz[(size_t)t * 3 + 0];
    float py = xyz[(size_t)t * 3 + 1];
    float pz = xyz[(size_t)t * 3 + 2];
    float ivx = 2.f / (aabb[3] - aabb[0]);
    float ivy = 2.f / (aabb[4] - aabb[1]);
    float ivz = 2.f / (aabb[5] - aabb[2]);
    int c = cell_of(px, py, pz, aabb[0], aabb[1], aabb[2], ivx, ivy, ivz);
    atomicAdd(&hist[c], 1);
  }
}

__global__ __launch_bounds__(256) void prep_lines(
    const float* __restrict__ dl, const float* __restrict__ al,
    half16_t* __restrict__ out)
{
  int t = blockIdx.x * blockDim.x + threadIdx.x;
  if (t >= 3 * G * 4) return;
  int m   = t & 3;
  int tex = t >> 2;
  int p = tex % G;
  int i = tex / G;
  h8 v;
#pragma unroll
  for (int c = 0; c < 8; ++c)
    v[c] = (m == 0) ? (half16_t)dl[(i * 8 + c) * G + p]
                    : (half16_t)al[(i * 24 + (m - 1) * 8 + c) * G + p];
  *(h8*)(out + (size_t)tex * CT + m * 8) = v;
}

// ---------------------------------------------------------------------------
// Exclusive prefix over 4096 cell counts. One block, 1024 threads, 4 cells each.
// ---------------------------------------------------------------------------
__global__ __launch_bounds__(1024) void prefix4096(
    const int* __restrict__ hist, int* __restrict__ offs)
{
  __shared__ int lds[1024];
  int tid = threadIdx.x;
  int4 h = ((const int4*)hist)[tid];
  int s = h.x + h.y + h.z + h.w;
  lds[tid] = s;
  __syncthreads();
#pragma unroll
  for (int off = 1; off < 1024; off <<= 1) {
    int u = 0;
    if (tid >= off) u = lds[tid - off];
    __syncthreads();
    if (tid >= off) lds[tid] += u;
    __syncthreads();
  }
  int excl = lds[tid] - s;   // exclusive prefix of this thread's 4-group
  int4 o;
  o.x = excl;
  o.y = o.x + h.x;
  o.z = o.y + h.y;
  o.w = o.z + h.z;
  ((int4*)offs)[tid] = o;
}

// ---------------------------------------------------------------------------
// Scatter: sorted_xyz[pos] = (x, y, z, bitcast(sample_id)).  Coalesced reads,
// one 16B scattered store per sample. offs consumed as allocation cursors.
// ---------------------------------------------------------------------------
__global__ __launch_bounds__(256) void scatter_sorted(
    const float* __restrict__ xyz, const float* __restrict__ aabb,
    int* __restrict__ offs, f4v* __restrict__ sxyz)
{
  int t = blockIdx.x * blockDim.x + threadIdx.x;
  if (t >= NSAMP) return;
  float px = xyz[(size_t)t * 3 + 0];
  float py = xyz[(size_t)t * 3 + 1];
  float pz = xyz[(size_t)t * 3 + 2];
  float ivx = 2.f / (aabb[3] - aabb[0]);
  float ivy = 2.f / (aabb[4] - aabb[1]);
  float ivz = 2.f / (aabb[5] - aabb[2]);
  int c = cell_of(px, py, pz, aabb[0], aabb[1], aabb[2], ivx, ivy, ivz);
  int pos = atomicAdd(&offs[c], 1);
  f4v v = {px, py, pz, __int_as_float(t)};
  __builtin_nontemporal_store(v, sxyz + pos);
}

// ---------------------------------------------------------------------------
// Gather over SORTED samples: quartet (4 lanes) per sample, 8 channels/lane.
// XCD-contiguous chunk swizzle: block b -> sorted range [(b&7)*512 + b>>3].
// NOTE: plain __launch_bounds__(256) — a min-waves hint spills W[3][24] (R2).
// ---------------------------------------------------------------------------
#define ITER 4

__global__ __launch_bounds__(256) void tensorf_gather(
    const f4v* __restrict__ sxyz,
    const half16_t* __restrict__ planes, const half16_t* __restrict__ lns,
    const float* __restrict__ dbw, const float* __restrict__ abw,
    const float* __restrict__ aabb, f4v* __restrict__ feat)
{
  const int lane = threadIdx.x & 63;
  const int wv   = threadIdx.x >> 6;
  const int q    = lane >> 2;   // quartet id within wave: sample slot
  const int r    = lane & 3;    // channel group: 0 = density ch0-7, 1..3 = app
  // XCD-contiguous swizzle: consecutive sorted cells stay on one XCD's L2
  const int cb   = (blockIdx.x & 7) * (gridDim.x >> 3) + (blockIdx.x >> 3);

  float W[3][24];
  if (r == 0) {
#pragma unroll
    for (int m = 0; m < 24; ++m) { W[0][m] = dbw[m]; W[1][m] = 0.f; W[2][m] = 0.f; }
  } else {
#pragma unroll
    for (int j = 0; j < 3; ++j)
#pragma unroll
      for (int i = 0; i < 3; ++i)
#pragma unroll
        for (int k = 0; k < 8; ++k)
          W[j][i * 8 + k] = abw[j * 72 + i * 24 + (r - 1) * 8 + k];
  }

  const float a0x = aabb[0], a0y = aabb[1], a0z = aabb[2];
  const float ivx = 2.f / (aabb[3] - aabb[0]);
  const float ivy = 2.f / (aabb[4] - aabb[1]);
  const float ivz = 2.f / (aabb[5] - aabb[2]);

  const int MA[3] = {0, 0, 1};   // MAT_MODE first
  const int MB[3] = {1, 2, 2};   // MAT_MODE second
  const int MV[3] = {2, 1, 0};   // VEC_MODE
  const int ro = r * 8;

#pragma unroll 1
  for (int it = 0; it < ITER; ++it) {
    int slot = (cb * 16 + wv * ITER + it) * 16 + q;   // sorted sample slot
    f4v sx = sxyz[slot];
    float px = sx.x, py = sx.y, pz = sx.z;
    int id = __float_as_int(sx.w);
    float g[3];
    g[0] = (px - a0x) * ivx - 1.f;
    g[1] = (py - a0y) * ivy - 1.f;
    g[2] = (pz - a0z) * ivz - 1.f;

    float acc0 = 0.f, acc1 = 0.f, acc2 = 0.f;
#pragma unroll
    for (int i = 0; i < 3; ++i) {
      float fx = (g[MA[i]] + 1.f) * (0.5f * (G - 1));
      float fy = (g[MB[i]] + 1.f) * (0.5f * (G - 1));
      float ft = (g[MV[i]] + 1.f) * (0.5f * (G - 1));
      float x0f = floorf(fx), y0f = floorf(fy), t0f = floorf(ft);
      float wx = fx - x0f, wy = fy - y0f, wt = ft - t0f;
      int x0 = min(max((int)x0f, 0), G - 1);
      int y0 = min(max((int)y0f, 0), G - 1);
      int t0 = min(max((int)t0f, 0), G - 1);
      int x1 = min(x0 + 1, G - 1);
      int y1 = min(y0 + 1, G - 1);
      int t1 = min(t0 + 1, G - 1);

      const half16_t* pb = planes + (size_t)i * G * G * CT;
      h8 t00 = *(const h8*)(pb + ((size_t)(y0 * G + x0)) * CT + ro);
      h8 t01 = *(const h8*)(pb + ((size_t)(y0 * G + x1)) * CT + ro);
      h8 t10 = *(const h8*)(pb + ((size_t)(y1 * G + x0)) * CT + ro);
      h8 t11 = *(const h8*)(pb + ((size_t)(y1 * G + x1)) * CT + ro);
      const half16_t* lb = lns + (size_t)i * G * CT + ro;
      h8 l0 = *(const h8*)(lb + (size_t)t0 * CT);
      h8 l1 = *(const h8*)(lb + (size_t)t1 * CT);

      float w00 = (1.f - wx) * (1.f - wy), w01 = wx * (1.f - wy);
      float w10 = (1.f - wx) * wy,         w11 = wx * wy;
      float wl0 = 1.f - wt;
#pragma unroll
      for (int k = 0; k < 8; ++k) {
        float pf = (float)t00[k] * w00 + (float)t01[k] * w01
                 + (float)t10[k] * w10 + (float)t11[k] * w11;
        float lf = (float)l0[k] * wl0 + (float)l1[k] * wt;
        float f  = pf * lf;
        acc0 += W[0][i * 8 + k] * f;
        acc1 += W[1][i * 8 + k] * f;
        acc2 += W[2][i * 8 + k] * f;
      }
    }
    f4v v;
    v.x = (r == 0) ? acc0 : 0.f;
    v.y = (r == 0) ? 0.f : acc0;
    v.z = (r == 0) ? 0.f : acc1;
    v.w = (r == 0) ? 0.f : acc2;
#pragma unroll
    for (int m = 1; m <= 2; m <<= 1) {
      v.x += __shfl_xor(v.x, m);
      v.y += __shfl_xor(v.y, m);
      v.z += __shfl_xor(v.z, m);
      v.w += __shfl_xor(v.w, m);
    }
    if (r == 0) __builtin_nontemporal_store(v, feat + id);
  }
}

// ---------------------------------------------------------------------------
// Scan: wave per ray, transmittance prefix-product + weighted rgb reduce.
// ---------------------------------------------------------------------------
__global__ __launch_bounds__(256) void tensorf_scan(
    const float* __restrict__ zv, const f4v* __restrict__ feat,
    float* __restrict__ out)
{
  const int wv   = threadIdx.x >> 6;
  const int lane = threadIdx.x & 63;
  const int ray  = (blockIdx.x << 2) + wv;

  const f4v* zp = (const f4v*)(zv + (size_t)ray * NS + lane * 4);
  f4v z4 = __builtin_nontemporal_load(zp);
  float znext = __shfl_down(z4.x, 1);
  float d[4];
  d[0] = z4.y - z4.x;
  d[1] = z4.z - z4.y;
  d[2] = z4.w - z4.z;
  d[3] = (lane == 63) ? d[2] : (znext - z4.w);

  f4v c[4];
  float al[4];
  float tl = 1.f;
#pragma unroll
  for (int j = 0; j < 4; ++j) {
    c[j] = __builtin_nontemporal_load(feat + (size_t)ray * NS + lane * 4 + j);
    float vs = c[j].x - 10.0f;  // DENSITY_SHIFT
    float sp = (vs > 0.f) ? (vs + log1pf(expf(-vs))) : log1pf(expf(vs));
    al[j] = 1.f - expf(-sp * (d[j] * 25.0f));  // DISTANCE_SCALE
    tl *= (1.f - al[j] + 1e-10f);
  }
  float incl = tl;
#pragma unroll
  for (int off = 1; off < 64; off <<= 1) {
    float p = __shfl_up(incl, off);
    if (lane >= off) incl *= p;
  }
  float T = __shfl_up(incl, 1);
  if (lane == 0) T = 1.f;

  float ar = 0.f, ag = 0.f, ab = 0.f;
#pragma unroll
  for (int j = 0; j < 4; ++j) {
    float w = al[j] * T;
    ar += w * c[j].y;
    ag += w * c[j].z;
    ab += w * c[j].w;
    T *= (1.f - al[j] + 1e-10f);
  }
#pragma unroll
  for (int off = 32; off > 0; off >>= 1) {
    ar += __shfl_down(ar, off);
    ag += __shfl_down(ag, off);
    ab += __shfl_down(ab, off);
  }
  if (lane == 0) {
    out[ray * 3 + 0] = ar;
    out[ray * 3 + 1] = ag;
    out[ray * 3 + 2] = ab;
  }
}

// ---------------------------------------------------------------------------
extern "C" void kernel_launch(void* const* d_in, const int* in_sizes, int n_in,
                              void* d_out, int out_size, void* d_ws, size_t ws_size,
                              hipStream_t stream)
{
  const float* xyz  = (const float*)d_in[0];
  const float* zv   = (const float*)d_in[2];
  const float* dp   = (const float*)d_in[3];
  const float* dl   = (const float*)d_in[4];
  const float* ap   = (const float*)d_in[5];
  const float* al   = (const float*)d_in[6];
  const float* dbw  = (const float*)d_in[7];
  const float* abw  = (const float*)d_in[8];
  const float* aabb = (const float*)d_in[9];
  float* out = (float*)d_out;

  // workspace layout (16B aligned)
  char* w = (char*)d_ws;
  half16_t* planes16 = (half16_t*)w;                 w += (size_t)3 * G * G * CT * 2;  // 17,280,000
  half16_t* lines16  = (half16_t*)w;                 w += (size_t)3 * G * CT * 2;      //     57,600
  f4v*      feat     = (f4v*)w;                      w += (size_t)NSAMP * 16;          // 16,777,216
  f4v*      sxyz     = (f4v*)w;                      w += (size_t)NSAMP * 16;          // 16,777,216
  int*      hist     = (int*)w;                      w += (size_t)NCELL * 4;           //     16,384
  int*      offs     = (int*)w;                      w += (size_t)NCELL * 4;           //     16,384

  hipMemsetAsync(hist, 0, NCELL * sizeof(int), stream);
  hipLaunchKernelGGL(prep_planes_hist, dim3((3 * G * G * 4 + 255) / 256), dim3(256), 0, stream,
                     dp, ap, xyz, aabb, planes16, hist);
  hipLaunchKernelGGL(prep_lines, dim3((3 * G * 4 + 255) / 256), dim3(256), 0, stream,
                     dl, al, lines16);
  hipLaunchKernelGGL(prefix4096, dim3(1), dim3(1024), 0, stream, hist, offs);
  hipLaunchKernelGGL(scatter_sorted, dim3((NSAMP + 255) / 256), dim3(256), 0, stream,
                     xyz, aabb, offs, sxyz);
  // 1M samples / (16 samples * ITER * 4 waves) = 4096 blocks
  hipLaunchKernelGGL(tensorf_gather, dim3(NSAMP / (16 * ITER * 4)), dim3(256), 0, stream,
                     sxyz, planes16, lines16, dbw, abw, aabb, feat);
  hipLaunchKernelGGL(tensorf_scan, dim3(NR / 4), dim3(256), 0, stream,
                     zv, feat, out);
}

// Round 5
// 281.055 us; speedup vs baseline: 1.2843x; 1.2843x over previous
//
#include <hip/hip_runtime.h>
#include <math.h>

#define G  300
#define NS 256
#define NR 4096
#define CT 32            // interleaved texel channels: 0-7 density, 8-31 app
#define NB 16            // bins per axis
#define NCELL (NB*NB*NB)
#define NSAMP (NR*NS)
#define CAP 384          // slots per cell: mean 256, sd 16 -> +8 sd, P(overflow)~1e-12

typedef _Float16 half16_t;
typedef _Float16 h2 __attribute__((ext_vector_type(2)));
typedef _Float16 h8 __attribute__((ext_vector_type(8)));
typedef float f4v __attribute__((ext_vector_type(4)));

#if __has_builtin(__builtin_amdgcn_fdot2)
#define FDOT2(a, b, c) __builtin_amdgcn_fdot2((a), (b), (c), false)
#else
#define FDOT2(a, b, c) ((c) + (float)(a)[0] * (float)(b)[0] + (float)(a)[1] * (float)(b)[1])
#endif

static __device__ __forceinline__ h8 splat8(float f) {
  half16_t h = (half16_t)f;
  h8 r = {h, h, h, h, h, h, h, h};
  return r;
}

// ---------------------------------------------------------------------------
// Prep: fp16-interleave planes [i][y][x][c32] + lines, and zero cell counters.
// One thread per 16B texel-part (8 channels): coalesced 16B stores.
// ---------------------------------------------------------------------------
__global__ __launch_bounds__(256) void prep_all(
    const float* __restrict__ dp, const float* __restrict__ ap,
    const float* __restrict__ dl, const float* __restrict__ al,
    half16_t* __restrict__ planes, half16_t* __restrict__ lines,
    int* __restrict__ cnt)
{
  int t = blockIdx.x * blockDim.x + threadIdx.x;
  if (t < 3 * G * G * 4) {
    int m   = t & 3;        // 8-channel part: 0=density, 1..3=app
    int tex = t >> 2;
    int x  = tex % G;
    int yi = tex / G;
    int y  = yi % G;
    int i  = yi / G;
    const size_t GG = (size_t)G * G;
    const float* p = (m == 0) ? (dp + (size_t)(i * 8) * GG + (size_t)y * G + x)
                              : (ap + (size_t)(i * 24 + (m - 1) * 8) * GG + (size_t)y * G + x);
    h8 v;
#pragma unroll
    for (int c = 0; c < 8; ++c) v[c] = (half16_t)p[c * GG];
    *(h8*)(planes + (size_t)tex * CT + m * 8) = v;
  }
  if (t < 3 * G * 4) {
    int m   = t & 3;
    int tex = t >> 2;
    int p = tex % G;
    int i = tex / G;
    h8 v;
#pragma unroll
    for (int c = 0; c < 8; ++c)
      v[c] = (m == 0) ? (half16_t)dl[(i * 8 + c) * G + p]
                      : (half16_t)al[(i * 24 + (m - 1) * 8 + c) * G + p];
    *(h8*)(lines + (size_t)tex * CT + m * 8) = v;
  }
  if (t < NCELL) cnt[t] = 0;
}

// ---------------------------------------------------------------------------
// Scatter into fixed-capacity cells. Stores PRE-SCALED texel coords
// (f = (g+1)*149.5 per axis) + sample id. Coalesced reads, one 16B
// scattered store + one atomic per sample. No hist/prefix passes needed.
// ---------------------------------------------------------------------------
__global__ __launch_bounds__(256) void scatter_cells(
    const float* __restrict__ xyz, const float* __restrict__ aabb,
    int* __restrict__ cnt, f4v* __restrict__ sxyz)
{
  int t = blockIdx.x * blockDim.x + threadIdx.x;
  if (t >= NSAMP) return;
  float ivx = 2.f / (aabb[3] - aabb[0]);
  float ivy = 2.f / (aabb[4] - aabb[1]);
  float ivz = 2.f / (aabb[5] - aabb[2]);
  float gx = (xyz[(size_t)t * 3 + 0] - aabb[0]) * ivx - 1.f;
  float gy = (xyz[(size_t)t * 3 + 1] - aabb[1]) * ivy - 1.f;
  float gz = (xyz[(size_t)t * 3 + 2] - aabb[2]) * ivz - 1.f;
  const float SC = 0.5f * (G - 1);
  float fx = (gx + 1.f) * SC;
  float fy = (gy + 1.f) * SC;
  float fz = (gz + 1.f) * SC;
  int bx = min(max((int)(fx * (NB / 300.0f)), 0), NB - 1);
  int by = min(max((int)(fy * (NB / 300.0f)), 0), NB - 1);
  int bz = min(max((int)(fz * (NB / 300.0f)), 0), NB - 1);
  int c = (bz * NB + by) * NB + bx;
  int pos = atomicAdd(&cnt[c], 1);
  if (pos < CAP) {
    f4v v = {fx, fy, fz, __int_as_float(t)};
    __builtin_nontemporal_store(v, sxyz + (size_t)c * CAP + pos);
  }
}

// ---------------------------------------------------------------------------
// Gather: one block per cell (4096 blocks). Quartet (4 lanes) per sample,
// 8 channels/lane. Packed-fp16 blends (v_pk_fma_f16) + v_dot2_f32_f16
// basis-weight reduction (f32 accumulate). W stored as h2 (36 VGPRs vs 72).
// XCD swizzle keeps 512 consecutive cells on one XCD's L2.
// NOTE: plain __launch_bounds__(256) — a min-waves hint spills W (R2 lesson).
// ---------------------------------------------------------------------------
__global__ __launch_bounds__(256) void tensorf_gather(
    const f4v* __restrict__ sxyz, const int* __restrict__ cnt,
    const half16_t* __restrict__ planes, const half16_t* __restrict__ lns,
    const float* __restrict__ dbw, const float* __restrict__ abw,
    f4v* __restrict__ feat)
{
  const int lane = threadIdx.x & 63;
  const int wv   = threadIdx.x >> 6;
  const int q    = lane >> 2;   // quartet id within wave
  const int r    = lane & 3;    // 0 = density ch0-7, 1..3 = app groups
  // XCD-contiguous swizzle: block b -> cell (b&7)*512 + b>>3
  const int cell = (blockIdx.x & 7) * (NCELL / 8) + (blockIdx.x >> 3);
  const int n    = min(cnt[cell], CAP);
  const size_t cbase = (size_t)cell * CAP;

  // Packed basis weights: wh{j}[i*4+p] covers channels 2p,2p+1 of this lane's
  // 8-channel group in mode i.
  h2 wh0[12], wh1[12], wh2[12];
  if (r == 0) {
#pragma unroll
    for (int m = 0; m < 12; ++m) {
      wh0[m][0] = (half16_t)dbw[2 * m];
      wh0[m][1] = (half16_t)dbw[2 * m + 1];
      wh1[m][0] = wh1[m][1] = wh2[m][0] = wh2[m][1] = (half16_t)0.f;
    }
  } else {
    const float* w0 = abw + 0 * 72 + (r - 1) * 8;
    const float* w1 = abw + 1 * 72 + (r - 1) * 8;
    const float* w2 = abw + 2 * 72 + (r - 1) * 8;
#pragma unroll
    for (int i = 0; i < 3; ++i)
#pragma unroll
      for (int p = 0; p < 4; ++p) {
        wh0[i * 4 + p][0] = (half16_t)w0[i * 24 + 2 * p];
        wh0[i * 4 + p][1] = (half16_t)w0[i * 24 + 2 * p + 1];
        wh1[i * 4 + p][0] = (half16_t)w1[i * 24 + 2 * p];
        wh1[i * 4 + p][1] = (half16_t)w1[i * 24 + 2 * p + 1];
        wh2[i * 4 + p][0] = (half16_t)w2[i * 24 + 2 * p];
        wh2[i * 4 + p][1] = (half16_t)w2[i * 24 + 2 * p + 1];
      }
  }

  const int MA[3] = {0, 0, 1};   // col axis per mode
  const int MB[3] = {1, 2, 2};   // row axis per mode
  const int MV[3] = {2, 1, 0};   // line axis per mode
  const int ro = r * 8;

#pragma unroll 1
  for (int sb = 0; sb < n; sb += 64) {
    int idx = sb + wv * 16 + q;
    bool valid = idx < n;
    f4v sx = sxyz[cbase + min(idx, n - 1)];
    int id = __float_as_int(sx.w);

    // per-axis floor/clamp done ONCE (not per mode)
    int   X0[3], X1[3];
    float WF[3];
#pragma unroll
    for (int a = 0; a < 3; ++a) {
      float f  = (a == 0) ? sx.x : (a == 1) ? sx.y : sx.z;
      float f0 = floorf(f);
      WF[a] = f - f0;
      X0[a] = min(max((int)f0, 0), G - 1);
      X1[a] = min(X0[a] + 1, G - 1);
    }

    float acc0 = 0.f, acc1 = 0.f, acc2 = 0.f;
#pragma unroll
    for (int i = 0; i < 3; ++i) {
      int c0 = X0[MA[i]], c1 = X1[MA[i]];
      int r0 = X0[MB[i]], r1 = X1[MB[i]];
      float wx = WF[MA[i]], wy = WF[MB[i]], wt = WF[MV[i]];

      const half16_t* pb = planes + (size_t)i * G * G * CT;
      h8 t00 = *(const h8*)(pb + ((size_t)(r0 * G + c0)) * CT + ro);
      h8 t01 = *(const h8*)(pb + ((size_t)(r0 * G + c1)) * CT + ro);
      h8 t10 = *(const h8*)(pb + ((size_t)(r1 * G + c0)) * CT + ro);
      h8 t11 = *(const h8*)(pb + ((size_t)(r1 * G + c1)) * CT + ro);
      const half16_t* lb = lns + (size_t)i * G * CT + ro;
      h8 l0 = *(const h8*)(lb + (size_t)X0[MV[i]] * CT);
      h8 l1 = *(const h8*)(lb + (size_t)X1[MV[i]] * CT);

      // packed fp16 bilinear + line blend (v_pk_fma_f16)
      h8 pf = t00 * splat8((1.f - wx) * (1.f - wy))
            + t01 * splat8(wx * (1.f - wy))
            + t10 * splat8((1.f - wx) * wy)
            + t11 * splat8(wx * wy);
      h8 lf = l0 * splat8(1.f - wt) + l1 * splat8(wt);
      h8 f  = pf * lf;

      // v_dot2_f32_f16: fp16 pair dot, f32 accumulate
#pragma unroll
      for (int p = 0; p < 4; ++p) {
        h2 fp = {f[2 * p], f[2 * p + 1]};
        acc0 = FDOT2(fp, wh0[i * 4 + p], acc0);
        acc1 = FDOT2(fp, wh1[i * 4 + p], acc1);
        acc2 = FDOT2(fp, wh2[i * 4 + p], acc2);
      }
    }

    // pack (sigma_feat, r, g, b) and reduce across the quartet
    f4v v;
    v.x = (r == 0) ? acc0 : 0.f;
    v.y = (r == 0) ? 0.f : acc0;
    v.z = (r == 0) ? 0.f : acc1;
    v.w = (r == 0) ? 0.f : acc2;
#pragma unroll
    for (int m = 1; m <= 2; m <<= 1) {
      v.x += __shfl_xor(v.x, m);
      v.y += __shfl_xor(v.y, m);
      v.z += __shfl_xor(v.z, m);
      v.w += __shfl_xor(v.w, m);
    }
    if (valid && r == 0) __builtin_nontemporal_store(v, feat + id);
  }
}

// ---------------------------------------------------------------------------
// Scan: wave per ray, transmittance prefix-product + weighted rgb reduce.
// ---------------------------------------------------------------------------
__global__ __launch_bounds__(256) void tensorf_scan(
    const float* __restrict__ zv, const f4v* __restrict__ feat,
    float* __restrict__ out)
{
  const int wv   = threadIdx.x >> 6;
  const int lane = threadIdx.x & 63;
  const int ray  = (blockIdx.x << 2) + wv;

  const f4v* zp = (const f4v*)(zv + (size_t)ray * NS + lane * 4);
  f4v z4 = __builtin_nontemporal_load(zp);
  float znext = __shfl_down(z4.x, 1);
  float d[4];
  d[0] = z4.y - z4.x;
  d[1] = z4.z - z4.y;
  d[2] = z4.w - z4.z;
  d[3] = (lane == 63) ? d[2] : (znext - z4.w);

  f4v c[4];
  float al[4];
  float tl = 1.f;
#pragma unroll
  for (int j = 0; j < 4; ++j) {
    c[j] = __builtin_nontemporal_load(feat + (size_t)ray * NS + lane * 4 + j);
    float vs = c[j].x - 10.0f;  // DENSITY_SHIFT
    float sp = (vs > 0.f) ? (vs + log1pf(expf(-vs))) : log1pf(expf(vs));
    al[j] = 1.f - expf(-sp * (d[j] * 25.0f));  // DISTANCE_SCALE
    tl *= (1.f - al[j] + 1e-10f);
  }
  float incl = tl;
#pragma unroll
  for (int off = 1; off < 64; off <<= 1) {
    float p = __shfl_up(incl, off);
    if (lane >= off) incl *= p;
  }
  float T = __shfl_up(incl, 1);
  if (lane == 0) T = 1.f;

  float ar = 0.f, ag = 0.f, ab = 0.f;
#pragma unroll
  for (int j = 0; j < 4; ++j) {
    float w = al[j] * T;
    ar += w * c[j].y;
    ag += w * c[j].z;
    ab += w * c[j].w;
    T *= (1.f - al[j] + 1e-10f);
  }
#pragma unroll
  for (int off = 32; off > 0; off >>= 1) {
    ar += __shfl_down(ar, off);
    ag += __shfl_down(ag, off);
    ab += __shfl_down(ab, off);
  }
  if (lane == 0) {
    out[ray * 3 + 0] = ar;
    out[ray * 3 + 1] = ag;
    out[ray * 3 + 2] = ab;
  }
}

// ---------------------------------------------------------------------------
extern "C" void kernel_launch(void* const* d_in, const int* in_sizes, int n_in,
                              void* d_out, int out_size, void* d_ws, size_t ws_size,
                              hipStream_t stream)
{
  const float* xyz  = (const float*)d_in[0];
  const float* zv   = (const float*)d_in[2];
  const float* dp   = (const float*)d_in[3];
  const float* dl   = (const float*)d_in[4];
  const float* ap   = (const float*)d_in[5];
  const float* al   = (const float*)d_in[6];
  const float* dbw  = (const float*)d_in[7];
  const float* abw  = (const float*)d_in[8];
  const float* aabb = (const float*)d_in[9];
  float* out = (float*)d_out;

  // workspace layout (16B aligned)
  char* w = (char*)d_ws;
  half16_t* planes16 = (half16_t*)w;  w += (size_t)3 * G * G * CT * 2;   // 17,280,000
  half16_t* lines16  = (half16_t*)w;  w += (size_t)3 * G * CT * 2;       //     57,600
  f4v*      feat     = (f4v*)w;       w += (size_t)NSAMP * 16;           // 16,777,216
  f4v*      sxyz     = (f4v*)w;       w += (size_t)NCELL * CAP * 16;     // 25,165,824
  int*      cnt      = (int*)w;       w += (size_t)NCELL * 4;            //     16,384

  hipLaunchKernelGGL(prep_all, dim3((3 * G * G * 4 + 255) / 256), dim3(256), 0, stream,
                     dp, ap, dl, al, planes16, lines16, cnt);
  hipLaunchKernelGGL(scatter_cells, dim3(NSAMP / 256), dim3(256), 0, stream,
                     xyz, aabb, cnt, sxyz);
  hipLaunchKernelGGL(tensorf_gather, dim3(NCELL), dim3(256), 0, stream,
                     sxyz, cnt, planes16, lines16, dbw, abw, feat);
  hipLaunchKernelGGL(tensorf_scan, dim3(NR / 4), dim3(256), 0, stream,
                     zv, feat, out);
}

// Round 6
// 269.509 us; speedup vs baseline: 1.3393x; 1.0428x over previous
//
#include <hip/hip_runtime.h>
#include <math.h>

#define G  300
#define NS 256
#define NR 4096
#define CT 32            // interleaved texel channels: 0-7 density, 8-31 app
#define NB 16            // bins per axis
#define NCELL (NB*NB*NB)
#define NSAMP (NR*NS)
#define CAP 384          // slots per cell: mean 256, sd 16 -> +8 sd, P(overflow)~1e-12
#define CPB 4            // cells per gather block

typedef _Float16 half16_t;
typedef _Float16 h2 __attribute__((ext_vector_type(2)));
typedef _Float16 h8 __attribute__((ext_vector_type(8)));
typedef float f4v __attribute__((ext_vector_type(4)));

#if __has_builtin(__builtin_amdgcn_fdot2)
#define FDOT2(a, b, c) __builtin_amdgcn_fdot2((a), (b), (c), false)
#else
#define FDOT2(a, b, c) ((c) + (float)(a)[0] * (float)(b)[0] + (float)(a)[1] * (float)(b)[1])
#endif

static __device__ __forceinline__ h8 splat8(float f) {
  half16_t h = (half16_t)f;
  h8 r = {h, h, h, h, h, h, h, h};
  return r;
}

// ---------------------------------------------------------------------------
// Fused prep + scatter. cnt must be zeroed beforehand (hipMemsetAsync).
//  - plane fp16 interleave: m = t / (3*G*G) so each wave's channel loads are
//    single-array, 64-lane consecutive (vs R5's t&3 which split every load
//    across 4 source arrays -> 4-way transaction splits).
//  - scatter: bin sample t, atomic cursor, store pre-scaled coords + id.
// ---------------------------------------------------------------------------
__global__ __launch_bounds__(256) void prep_scatter(
    const float* __restrict__ dp, const float* __restrict__ ap,
    const float* __restrict__ dl, const float* __restrict__ al,
    const float* __restrict__ xyz, const float* __restrict__ aabb,
    half16_t* __restrict__ planes, half16_t* __restrict__ lines,
    int* __restrict__ cnt, f4v* __restrict__ sxyz)
{
  const int NPP = 3 * G * G;   // texel count
  int t = blockIdx.x * blockDim.x + threadIdx.x;

  if (t < NPP * 4) {
    int m   = t / NPP;          // 8-channel part: 0=density, 1..3=app (wave-uniform-ish)
    int tex = t - m * NPP;
    int x  = tex % G;
    int yi = tex / G;
    int y  = yi % G;
    int i  = yi / G;
    const size_t GG = (size_t)G * G;
    const float* p = (m == 0) ? (dp + (size_t)(i * 8) * GG + (size_t)y * G + x)
                              : (ap + (size_t)(i * 24 + (m - 1) * 8) * GG + (size_t)y * G + x);
    h8 v;
#pragma unroll
    for (int c = 0; c < 8; ++c) v[c] = (half16_t)p[c * GG];
    *(h8*)(planes + (size_t)tex * CT + m * 8) = v;
  }

  if (t < 3 * G * 4) {
    int m   = t & 3;
    int tex = t >> 2;
    int p = tex % G;
    int i = tex / G;
    h8 v;
#pragma unroll
    for (int c = 0; c < 8; ++c)
      v[c] = (m == 0) ? (half16_t)dl[(i * 8 + c) * G + p]
                      : (half16_t)al[(i * 24 + (m - 1) * 8 + c) * G + p];
    *(h8*)(lines + (size_t)tex * CT + m * 8) = v;
  }

  if (t < NSAMP) {
    float ivx = 2.f / (aabb[3] - aabb[0]);
    float ivy = 2.f / (aabb[4] - aabb[1]);
    float ivz = 2.f / (aabb[5] - aabb[2]);
    float gx = (xyz[(size_t)t * 3 + 0] - aabb[0]) * ivx - 1.f;
    float gy = (xyz[(size_t)t * 3 + 1] - aabb[1]) * ivy - 1.f;
    float gz = (xyz[(size_t)t * 3 + 2] - aabb[2]) * ivz - 1.f;
    const float SC = 0.5f * (G - 1);
    float fx = (gx + 1.f) * SC;
    float fy = (gy + 1.f) * SC;
    float fz = (gz + 1.f) * SC;
    int bx = min(max((int)(fx * (NB / 300.0f)), 0), NB - 1);
    int by = min(max((int)(fy * (NB / 300.0f)), 0), NB - 1);
    int bz = min(max((int)(fz * (NB / 300.0f)), 0), NB - 1);
    int c = (bz * NB + by) * NB + bx;
    int pos = atomicAdd(&cnt[c], 1);
    if (pos < CAP) {
      f4v v = {fx, fy, fz, __int_as_float(t)};
      __builtin_nontemporal_store(v, sxyz + (size_t)c * CAP + pos);
    }
  }
}

// ---------------------------------------------------------------------------
// Gather: 1024 blocks x CPB=4 cells (longer-lived blocks than R5's 4096 for
// steadier residency). Quartet (4 lanes) per sample, 8 channels/lane.
// Packed-fp16 blends + v_dot2_f32_f16 reduction. unroll 2 for cross-iteration
// MLP (R5's unroll 1 capped outstanding loads at one iteration's worth).
// NOTE: plain __launch_bounds__(256) — a min-waves hint spills W (R2 lesson).
// ---------------------------------------------------------------------------
__global__ __launch_bounds__(256) void tensorf_gather(
    const f4v* __restrict__ sxyz, const int* __restrict__ cnt,
    const half16_t* __restrict__ planes, const half16_t* __restrict__ lns,
    const float* __restrict__ dbw, const float* __restrict__ abw,
    f4v* __restrict__ feat)
{
  const int lane = threadIdx.x & 63;
  const int wv   = threadIdx.x >> 6;
  const int q    = lane >> 2;   // quartet id within wave
  const int r    = lane & 3;    // 0 = density ch0-7, 1..3 = app groups
  // XCD-contiguous swizzle at chunk level: 128 consecutive chunks per XCD
  const int cb   = (blockIdx.x & 7) * ((NCELL / CPB) / 8) + (blockIdx.x >> 3);

  // Packed basis weights: wh{j}[i*4+p] covers channels 2p,2p+1 of this lane's
  // 8-channel group in mode i.
  h2 wh0[12], wh1[12], wh2[12];
  if (r == 0) {
#pragma unroll
    for (int m = 0; m < 12; ++m) {
      wh0[m][0] = (half16_t)dbw[2 * m];
      wh0[m][1] = (half16_t)dbw[2 * m + 1];
      wh1[m][0] = wh1[m][1] = wh2[m][0] = wh2[m][1] = (half16_t)0.f;
    }
  } else {
    const float* w0 = abw + 0 * 72 + (r - 1) * 8;
    const float* w1 = abw + 1 * 72 + (r - 1) * 8;
    const float* w2 = abw + 2 * 72 + (r - 1) * 8;
#pragma unroll
    for (int i = 0; i < 3; ++i)
#pragma unroll
      for (int p = 0; p < 4; ++p) {
        wh0[i * 4 + p][0] = (half16_t)w0[i * 24 + 2 * p];
        wh0[i * 4 + p][1] = (half16_t)w0[i * 24 + 2 * p + 1];
        wh1[i * 4 + p][0] = (half16_t)w1[i * 24 + 2 * p];
        wh1[i * 4 + p][1] = (half16_t)w1[i * 24 + 2 * p + 1];
        wh2[i * 4 + p][0] = (half16_t)w2[i * 24 + 2 * p];
        wh2[i * 4 + p][1] = (half16_t)w2[i * 24 + 2 * p + 1];
      }
  }

  const int MA[3] = {0, 0, 1};   // col axis per mode
  const int MB[3] = {1, 2, 2};   // row axis per mode
  const int MV[3] = {2, 1, 0};   // line axis per mode
  const int ro = r * 8;

#pragma unroll 1
  for (int cc = 0; cc < CPB; ++cc) {
    const int cell = cb * CPB + cc;
    const int n    = min(cnt[cell], CAP);
    const size_t cbase = (size_t)cell * CAP;

#pragma unroll 2
    for (int sb = 0; sb < n; sb += 64) {
      int idx = sb + wv * 16 + q;
      bool valid = idx < n;
      f4v sx = sxyz[cbase + min(idx, n - 1)];
      int id = __float_as_int(sx.w);

      // per-axis floor/clamp done ONCE (not per mode)
      int   X0[3], X1[3];
      float WF[3];
#pragma unroll
      for (int a = 0; a < 3; ++a) {
        float f  = (a == 0) ? sx.x : (a == 1) ? sx.y : sx.z;
        float f0 = floorf(f);
        WF[a] = f - f0;
        X0[a] = min(max((int)f0, 0), G - 1);
        X1[a] = min(X0[a] + 1, G - 1);
      }

      float acc0 = 0.f, acc1 = 0.f, acc2 = 0.f;
#pragma unroll
      for (int i = 0; i < 3; ++i) {
        int c0 = X0[MA[i]], c1 = X1[MA[i]];
        int r0 = X0[MB[i]], r1 = X1[MB[i]];
        float wx = WF[MA[i]], wy = WF[MB[i]], wt = WF[MV[i]];

        const half16_t* pb = planes + (size_t)i * G * G * CT;
        h8 t00 = *(const h8*)(pb + ((size_t)(r0 * G + c0)) * CT + ro);
        h8 t01 = *(const h8*)(pb + ((size_t)(r0 * G + c1)) * CT + ro);
        h8 t10 = *(const h8*)(pb + ((size_t)(r1 * G + c0)) * CT + ro);
        h8 t11 = *(const h8*)(pb + ((size_t)(r1 * G + c1)) * CT + ro);
        const half16_t* lb = lns + (size_t)i * G * CT + ro;
        h8 l0 = *(const h8*)(lb + (size_t)X0[MV[i]] * CT);
        h8 l1 = *(const h8*)(lb + (size_t)X1[MV[i]] * CT);

        // packed fp16 bilinear + line blend (v_pk_fma_f16)
        h8 pf = t00 * splat8((1.f - wx) * (1.f - wy))
              + t01 * splat8(wx * (1.f - wy))
              + t10 * splat8((1.f - wx) * wy)
              + t11 * splat8(wx * wy);
        h8 lf = l0 * splat8(1.f - wt) + l1 * splat8(wt);
        h8 f  = pf * lf;

        // v_dot2_f32_f16: fp16 pair dot, f32 accumulate
#pragma unroll
        for (int p = 0; p < 4; ++p) {
          h2 fp = {f[2 * p], f[2 * p + 1]};
          acc0 = FDOT2(fp, wh0[i * 4 + p], acc0);
          acc1 = FDOT2(fp, wh1[i * 4 + p], acc1);
          acc2 = FDOT2(fp, wh2[i * 4 + p], acc2);
        }
      }

      // pack (sigma_feat, r, g, b) and reduce across the quartet
      f4v v;
      v.x = (r == 0) ? acc0 : 0.f;
      v.y = (r == 0) ? 0.f : acc0;
      v.z = (r == 0) ? 0.f : acc1;
      v.w = (r == 0) ? 0.f : acc2;
#pragma unroll
      for (int m = 1; m <= 2; m <<= 1) {
        v.x += __shfl_xor(v.x, m);
        v.y += __shfl_xor(v.y, m);
        v.z += __shfl_xor(v.z, m);
        v.w += __shfl_xor(v.w, m);
      }
      if (valid && r == 0) __builtin_nontemporal_store(v, feat + id);
    }
  }
}

// ---------------------------------------------------------------------------
// Scan: wave per ray, transmittance prefix-product + weighted rgb reduce.
// ---------------------------------------------------------------------------
__global__ __launch_bounds__(256) void tensorf_scan(
    const float* __restrict__ zv, const f4v* __restrict__ feat,
    float* __restrict__ out)
{
  const int wv   = threadIdx.x >> 6;
  const int lane = threadIdx.x & 63;
  const int ray  = (blockIdx.x << 2) + wv;

  const f4v* zp = (const f4v*)(zv + (size_t)ray * NS + lane * 4);
  f4v z4 = __builtin_nontemporal_load(zp);
  float znext = __shfl_down(z4.x, 1);
  float d[4];
  d[0] = z4.y - z4.x;
  d[1] = z4.z - z4.y;
  d[2] = z4.w - z4.z;
  d[3] = (lane == 63) ? d[2] : (znext - z4.w);

  f4v c[4];
  float al[4];
  float tl = 1.f;
#pragma unroll
  for (int j = 0; j < 4; ++j) {
    c[j] = __builtin_nontemporal_load(feat + (size_t)ray * NS + lane * 4 + j);
    float vs = c[j].x - 10.0f;  // DENSITY_SHIFT
    float sp = (vs > 0.f) ? (vs + log1pf(expf(-vs))) : log1pf(expf(vs));
    al[j] = 1.f - expf(-sp * (d[j] * 25.0f));  // DISTANCE_SCALE
    tl *= (1.f - al[j] + 1e-10f);
  }
  float incl = tl;
#pragma unroll
  for (int off = 1; off < 64; off <<= 1) {
    float p = __shfl_up(incl, off);
    if (lane >= off) incl *= p;
  }
  float T = __shfl_up(incl, 1);
  if (lane == 0) T = 1.f;

  float ar = 0.f, ag = 0.f, ab = 0.f;
#pragma unroll
  for (int j = 0; j < 4; ++j) {
    float w = al[j] * T;
    ar += w * c[j].y;
    ag += w * c[j].z;
    ab += w * c[j].w;
    T *= (1.f - al[j] + 1e-10f);
  }
#pragma unroll
  for (int off = 32; off > 0; off >>= 1) {
    ar += __shfl_down(ar, off);
    ag += __shfl_down(ag, off);
    ab += __shfl_down(ab, off);
  }
  if (lane == 0) {
    out[ray * 3 + 0] = ar;
    out[ray * 3 + 1] = ag;
    out[ray * 3 + 2] = ab;
  }
}

// ---------------------------------------------------------------------------
extern "C" void kernel_launch(void* const* d_in, const int* in_sizes, int n_in,
                              void* d_out, int out_size, void* d_ws, size_t ws_size,
                              hipStream_t stream)
{
  const float* xyz  = (const float*)d_in[0];
  const float* zv   = (const float*)d_in[2];
  const float* dp   = (const float*)d_in[3];
  const float* dl   = (const float*)d_in[4];
  const float* ap   = (const float*)d_in[5];
  const float* al   = (const float*)d_in[6];
  const float* dbw  = (const float*)d_in[7];
  const float* abw  = (const float*)d_in[8];
  const float* aabb = (const float*)d_in[9];
  float* out = (float*)d_out;

  // workspace layout (16B aligned)
  char* w = (char*)d_ws;
  half16_t* planes16 = (half16_t*)w;  w += (size_t)3 * G * G * CT * 2;   // 17,280,000
  half16_t* lines16  = (half16_t*)w;  w += (size_t)3 * G * CT * 2;       //     57,600
  f4v*      feat     = (f4v*)w;       w += (size_t)NSAMP * 16;           // 16,777,216
  f4v*      sxyz     = (f4v*)w;       w += (size_t)NCELL * CAP * 16;     // 25,165,824
  int*      cnt      = (int*)w;       w += (size_t)NCELL * 4;            //     16,384

  hipMemsetAsync(cnt, 0, NCELL * sizeof(int), stream);
  hipLaunchKernelGGL(prep_scatter, dim3((3 * G * G * 4 + 255) / 256), dim3(256), 0, stream,
                     dp, ap, dl, al, xyz, aabb, planes16, lines16, cnt, sxyz);
  hipLaunchKernelGGL(tensorf_gather, dim3(NCELL / CPB), dim3(256), 0, stream,
                     sxyz, cnt, planes16, lines16, dbw, abw, feat);
  hipLaunchKernelGGL(tensorf_scan, dim3(NR / 4), dim3(256), 0, stream,
                     zv, feat, out);
}